// Round 2
// baseline (1897.473 us; speedup 1.0000x reference)
//
#include <hip/hip_runtime.h>
#include <hip/hip_bf16.h>
#include <hip/hip_cooperative_groups.h>
#include <math.h>

namespace cg = cooperative_groups;

#define BATCH 32
#define C 256
#define HW 3136
#define OUTROW 32896
#define KSPLIT 7
#define KCHUNK 448   // HW / KSPLIT
#define KC32 98      // HW / 32
#define KCG 49       // kc-pair groups per batch
#define SLAB 16384   // shorts per kc slab (hi 8192 + lo 8192 interleaved)
#define HALF 8192

// Interleaved fragment-major layouts (shorts):
//   X slab s = b*98 + kc :  X[s*SLAB + row*32 + (k&31)]        (hi)
//                           X[s*SLAB + HALF + row*32 + (k&31)] (lo)
//   M slab s = b*8 + kc  :  same, 256x256 matrices, 8 slabs each.
// hi/lo of a fragment are 16 KB apart -> same pages, one write stream in prep.

typedef __bf16 b8v __attribute__((ext_vector_type(8)));
typedef float  f4v __attribute__((ext_vector_type(4)));
typedef unsigned short u16x8 __attribute__((ext_vector_type(8)));

__device__ __forceinline__ unsigned short f2bf(float f) {
    union { float f; unsigned u; } v; v.f = f;
    unsigned r = v.u + 0x7FFFu + ((v.u >> 16) & 1u);
    return (unsigned short)(r >> 16);
}
__device__ __forceinline__ float bf2f(unsigned short h) {
    union { unsigned u; float f; } v; v.u = ((unsigned)h) << 16; return v.f;
}
__device__ __forceinline__ void split2(float x, unsigned short& h, unsigned short& l) {
    h = f2bf(x);
    l = f2bf(x - bf2f(h));
}

__device__ __forceinline__ float wave_sum(float v) {
    for (int o = 32; o; o >>= 1) v += __shfl_down(v, o, 64);
    return v;
}

// ---------------------------------------------------------------------------
// prep: x -> hi/lo bf16 split, interleaved fragment-major X layout.
// Block per (b, kc-pair): writes one contiguous 64-KB region (2 slabs);
// reads two adjacent 128-B segments per row (256-B window). Per-(b,row,kcg)
// sum/sumsq partials to psum/qsum.
// ---------------------------------------------------------------------------
__global__ __launch_bounds__(256) void k_prep(const float* __restrict__ x,
                                              unsigned short* __restrict__ X,
                                              float* __restrict__ psum,
                                              float* __restrict__ qsum) {
    const int blk = blockIdx.x;                 // b*KCG + g
    const int b = blk / KCG;
    const int g = blk - b * KCG;
    const int kc0 = g * 2;
    const int t = threadIdx.x;
    const int lane4 = t & 3;                    // 4 lanes per row, 16 floats each
    const int rowoff = t >> 2;                  // 0..63
    const int ko = lane4 * 8;

    const float* xb = x + (size_t)b * C * HW + (size_t)kc0 * 32 + ko;
    unsigned short* s0 = X + (size_t)(b * KC32 + kc0) * SLAB + ko;
    unsigned short* s1 = s0 + SLAB;
    float* ps = psum + (size_t)blk * 256;
    float* qs = qsum + (size_t)blk * 256;

#pragma unroll
    for (int it = 0; it < 4; ++it) {
        const int row = it * 64 + rowoff;
        const float* src = xb + (size_t)row * HW;
        float4 v0 = *(const float4*)(src);
        float4 v1 = *(const float4*)(src + 4);
        float4 v2 = *(const float4*)(src + 32);
        float4 v3 = *(const float4*)(src + 36);
        float va[8] = { v0.x, v0.y, v0.z, v0.w, v1.x, v1.y, v1.z, v1.w };
        float vb[8] = { v2.x, v2.y, v2.z, v2.w, v3.x, v3.y, v3.z, v3.w };
        unsigned short ha[8], la[8], hb[8], lb[8];
        float s = 0.f, q = 0.f;
#pragma unroll
        for (int j = 0; j < 8; ++j) {
            split2(va[j], ha[j], la[j]);
            split2(vb[j], hb[j], lb[j]);
            s += va[j] + vb[j];
            q = fmaf(va[j], va[j], q);
            q = fmaf(vb[j], vb[j], q);
        }
        *(u16x8*)(s0 + row * 32) = *(u16x8*)ha;
        *(u16x8*)(s0 + HALF + row * 32) = *(u16x8*)la;
        *(u16x8*)(s1 + row * 32) = *(u16x8*)hb;
        *(u16x8*)(s1 + HALF + row * 32) = *(u16x8*)lb;
        s += __shfl_xor(s, 1, 64);
        s += __shfl_xor(s, 2, 64);
        q += __shfl_xor(q, 1, 64);
        q += __shfl_xor(q, 2, 64);
        if (lane4 == 0) { ps[row] = s; qs[row] = q; }
    }
}

// reduce per-kcg partials -> sbuf (row sums) + trace
__global__ __launch_bounds__(256) void k_tr(const float* __restrict__ psum,
                                            const float* __restrict__ qsum,
                                            float* __restrict__ sbuf,
                                            float* __restrict__ trbuf,
                                            float* __restrict__ strbuf) {
    const int b = blockIdx.x, t = threadIdx.x;
    const float* ps = psum + (size_t)b * KCG * 256 + t;
    const float* qs = qsum + (size_t)b * KCG * 256 + t;
    float s = 0.f, q = 0.f;
#pragma unroll 7
    for (int g = 0; g < KCG; ++g) {
        s += ps[(size_t)g * 256];
        q += qs[(size_t)g * 256];
    }
    sbuf[b * C + t] = s;
    const float invn = 1.f / (float)HW, invn2 = invn * invn;
    float v = q * invn - s * s * invn2;
    v = wave_sum(v);
    __shared__ float red[4];
    if ((t & 63) == 0) red[t >> 6] = v;
    __syncthreads();
    if (t == 0) {
        float tr = red[0] + red[1] + red[2] + red[3];
        trbuf[b] = tr;
        strbuf[b] = sqrtf(tr);
    }
}

// ---------------------------------------------------------------------------
// gram split-K: 1-wave blocks, 64x64 tile, fragment-major coalesced loads,
// register dbuf, XCD-pinned. Grid 2240 x 64.
// ---------------------------------------------------------------------------
__global__ __launch_bounds__(64) void k_gram_split(
    const unsigned short* __restrict__ X, float* __restrict__ part) {
    const int bid = blockIdx.x;
    const int x8 = bid & 7;
    const int t8 = bid >> 3;
    const int pairIdx = t8 % 10;
    const int g = (t8 / 10) * 8 + x8;   // 0..223, pinned to XCD x8
    const int b = g & 31;
    const int z = g >> 5;               // 0..6

    int p = pairIdx, tm = 0, rem = 4;
    while (p >= rem) { p -= rem; ++tm; --rem; }
    const int tn = tm + p;

    const int lane = threadIdx.x & 63;
    const int q = lane >> 4, r = lane & 15;
    const int kc0 = z * (KCHUNK / 32);
    const size_t matb = (size_t)b * KC32 * SLAB;

    int oA[4], oB[4];
#pragma unroll
    for (int i = 0; i < 4; ++i) {
        oA[i] = (tm * 64 + i * 16 + r) * 32 + q * 8;
        oB[i] = (tn * 64 + i * 16 + r) * 32 + q * 8;
    }

    f4v acc[4][4] = {};
    b8v fAh[2][4], fAl[2][4], fBh[2][4], fBl[2][4];
#define LDG(buf, kc)                                                     \
    do {                                                                 \
        const size_t sb = matb + (size_t)(kc0 + (kc)) * SLAB;            \
        for (int i = 0; i < 4; ++i) {                                    \
            fAh[buf][i] = *(const b8v*)(X + sb + oA[i]);                 \
            fAl[buf][i] = *(const b8v*)(X + sb + HALF + oA[i]);          \
            fBh[buf][i] = *(const b8v*)(X + sb + oB[i]);                 \
            fBl[buf][i] = *(const b8v*)(X + sb + HALF + oB[i]);          \
        }                                                                \
    } while (0)

    LDG(0, 0);
#pragma unroll
    for (int kc = 0; kc < KCHUNK / 32; ++kc) {
        const int cb = kc & 1, nb = cb ^ 1;
        if (kc < KCHUNK / 32 - 1) LDG(nb, kc + 1);
#pragma unroll
        for (int i = 0; i < 4; ++i)
#pragma unroll
            for (int j = 0; j < 4; ++j) {
                acc[i][j] = __builtin_amdgcn_mfma_f32_16x16x32_bf16(fAh[cb][i], fBh[cb][j], acc[i][j], 0, 0, 0);
                acc[i][j] = __builtin_amdgcn_mfma_f32_16x16x32_bf16(fAh[cb][i], fBl[cb][j], acc[i][j], 0, 0, 0);
                acc[i][j] = __builtin_amdgcn_mfma_f32_16x16x32_bf16(fAl[cb][i], fBh[cb][j], acc[i][j], 0, 0, 0);
            }
    }
#undef LDG

    float* pt = part + (((size_t)pairIdx * BATCH + b) * KSPLIT + z) * 4096;
#pragma unroll
    for (int i = 0; i < 4; ++i)
#pragma unroll
        for (int j = 0; j < 4; ++j)
#pragma unroll
            for (int reg = 0; reg < 4; ++reg) {
                int row = i * 16 + q * 4 + reg;
                int col = j * 16 + r;
                pt[row * 64 + col] = acc[i][j][reg];
            }
}

// ---------------------------------------------------------------------------
// reduce partials -> a and z0 (interleaved fragment-major), mirrored via LDS
// ---------------------------------------------------------------------------
__global__ __launch_bounds__(256) void k_reduce(
    const float* __restrict__ part, const float* __restrict__ sbuf,
    const float* __restrict__ trbuf,
    unsigned short* __restrict__ A, unsigned short* __restrict__ Z) {
    const int b = blockIdx.y;
    int p = blockIdx.x, tm = 0, rem = 4;
    while (p >= rem) { p -= rem; ++tm; --rem; }
    const int tn = tm + p;

    const float* pb = part + ((size_t)blockIdx.x * BATCH + b) * KSPLIT * 4096;
    const int t = threadIdx.x;
    const int row = t >> 2, c0 = (t & 3) * 16;

    float s[16];
#pragma unroll
    for (int u = 0; u < 16; ++u) s[u] = 0.f;
    for (int sp = 0; sp < KSPLIT; ++sp) {
        const float* q4 = pb + sp * 4096 + row * 64 + c0;
#pragma unroll
        for (int u4 = 0; u4 < 4; ++u4) {
            float4 v = *(const float4*)(q4 + u4 * 4);
            s[u4 * 4 + 0] += v.x; s[u4 * 4 + 1] += v.y;
            s[u4 * 4 + 2] += v.z; s[u4 * 4 + 3] += v.w;
        }
    }

    const float invn = 1.f / (float)HW, invn2 = invn * invn;
    const float tr = trbuf[b];
    const int gi = tm * 64 + row;
    const float si = sbuf[b * C + gi];
    const size_t mb = (size_t)b * 8 * SLAB;

    __shared__ unsigned short tAh[64][66], tAl[64][66], tZh[64][66], tZl[64][66];
    unsigned short vAh[16], vAl[16], vZh[16], vZl[16];
#pragma unroll
    for (int u = 0; u < 16; ++u) {
        int gj = tn * 64 + c0 + u;
        float sj = sbuf[b * C + gj];
        float a = (s[u] * invn - si * sj * invn2) / tr;
        split2(a, vAh[u], vAl[u]);
        float zv = ((gi == gj) ? 1.5f : 0.f) - 0.5f * a;
        split2(zv, vZh[u], vZl[u]);
        tAh[row][c0 + u] = vAh[u]; tAl[row][c0 + u] = vAl[u];
        tZh[row][c0 + u] = vZh[u]; tZl[row][c0 + u] = vZl[u];
    }
#pragma unroll
    for (int u4 = 0; u4 < 4; ++u4) {
        const int col0 = tn * 64 + c0 + u4 * 4;
        const size_t off = mb + (size_t)(col0 >> 5) * SLAB + (size_t)gi * 32 + (col0 & 31);
        *(ushort4*)&A[off] = *(ushort4*)&vAh[u4 * 4];
        *(ushort4*)&A[off + HALF] = *(ushort4*)&vAl[u4 * 4];
        *(ushort4*)&Z[off] = *(ushort4*)&vZh[u4 * 4];
        *(ushort4*)&Z[off + HALF] = *(ushort4*)&vZl[u4 * 4];
    }
    if (tm != tn) {
        __syncthreads();
        const int mr = t >> 2, mc0 = (t & 3) * 16;
        const int gim = tn * 64 + mr;
        unsigned short wAh[16], wAl[16], wZh[16], wZl[16];
#pragma unroll
        for (int u = 0; u < 16; ++u) {
            wAh[u] = tAh[mc0 + u][mr]; wAl[u] = tAl[mc0 + u][mr];
            wZh[u] = tZh[mc0 + u][mr]; wZl[u] = tZl[mc0 + u][mr];
        }
#pragma unroll
        for (int u4 = 0; u4 < 4; ++u4) {
            const int col0 = tm * 64 + mc0 + u4 * 4;
            const size_t off = mb + (size_t)(col0 >> 5) * SLAB + (size_t)gim * 32 + (col0 & 31);
            *(ushort4*)&A[off] = *(ushort4*)&wAh[u4 * 4];
            *(ushort4*)&A[off + HALF] = *(ushort4*)&wAl[u4 * 4];
            *(ushort4*)&Z[off] = *(ushort4*)&wZh[u4 * 4];
            *(ushort4*)&Z[off + HALF] = *(ushort4*)&wZl[u4 * 4];
        }
    }
}

// ---------------------------------------------------------------------------
// NS core: one wave, 64x64 tile, K=256, interleaved fragment-major loads,
// register dbuf. No LDS, no barriers.
// ---------------------------------------------------------------------------
__device__ __forceinline__ void wave_gemm64(
    const unsigned short* __restrict__ A, const unsigned short* __restrict__ B,
    int rowA, int rowB, f4v acc[4][4]) {
    const int lane = threadIdx.x & 63;
    const int q = lane >> 4, r = lane & 15;
    int oA[4], oB[4];
#pragma unroll
    for (int i = 0; i < 4; ++i) {
        oA[i] = (rowA + i * 16 + r) * 32 + q * 8;
        oB[i] = (rowB + i * 16 + r) * 32 + q * 8;
    }
    b8v fAh[2][4], fAl[2][4], fBh[2][4], fBl[2][4];
#define LD(buf, kc)                                              \
    do {                                                         \
        const size_t sb = (size_t)(kc) * SLAB;                   \
        for (int i = 0; i < 4; ++i) {                            \
            fAh[buf][i] = *(const b8v*)(A + sb + oA[i]);         \
            fAl[buf][i] = *(const b8v*)(A + sb + HALF + oA[i]);  \
            fBh[buf][i] = *(const b8v*)(B + sb + oB[i]);         \
            fBl[buf][i] = *(const b8v*)(B + sb + HALF + oB[i]);  \
        }                                                        \
    } while (0)

    LD(0, 0);
#pragma unroll
    for (int kc = 0; kc < 8; ++kc) {
        const int cb = kc & 1, nb = cb ^ 1;
        if (kc < 7) LD(nb, kc + 1);
#pragma unroll
        for (int i = 0; i < 4; ++i)
#pragma unroll
            for (int j = 0; j < 4; ++j) {
                acc[i][j] = __builtin_amdgcn_mfma_f32_16x16x32_bf16(fAh[cb][i], fBh[cb][j], acc[i][j], 0, 0, 0);
                acc[i][j] = __builtin_amdgcn_mfma_f32_16x16x32_bf16(fAh[cb][i], fBl[cb][j], acc[i][j], 0, 0, 0);
                acc[i][j] = __builtin_amdgcn_mfma_f32_16x16x32_bf16(fAl[cb][i], fBh[cb][j], acc[i][j], 0, 0, 0);
            }
    }
#undef LD
}

// store one 64x64 result tile into interleaved fragment-major D
__device__ __forceinline__ void store_tile_fm(
    unsigned short* __restrict__ D, int tm, int tn, const f4v acc[4][4], bool modeT) {
    const int lane = threadIdx.x & 63, q = lane >> 4, r = lane & 15;
#pragma unroll
    for (int i = 0; i < 4; ++i)
#pragma unroll
        for (int j = 0; j < 4; ++j) {
            const int gj = tn * 64 + j * 16 + r;
            const size_t cbase = (size_t)(gj >> 5) * SLAB + (gj & 31);
#pragma unroll
            for (int reg = 0; reg < 4; ++reg) {
                const int gi = tm * 64 + i * 16 + q * 4 + reg;
                float v = acc[i][j][reg];
                if (modeT) v = ((gi == gj) ? 1.5f : 0.f) - 0.5f * v;
                unsigned short h, l;
                split2(v, h, l);
                D[cbase + (size_t)gi * 32] = h;
                D[cbase + HALF + (size_t)gi * 32] = l;
            }
        }
}

// ---------------------------------------------------------------------------
// Fused NS chain: 9 stages separated by grid.sync(). 1024 blocks x 1 wave
// (4 waves/CU co-resident). Batch b stays pinned to XCD b%8 across stages ->
// inter-stage matrix traffic stays in that XCD's L2.
// stage types: 0 = plain GEMM, 1 = T-GEMM (1.5I-0.5*), 2 = YZ pair, 3 = triu out
// ---------------------------------------------------------------------------
__global__ __launch_bounds__(64) void k_ns(
    unsigned short* __restrict__ PA, unsigned short* __restrict__ PB,
    unsigned short* __restrict__ PC, unsigned short* __restrict__ PD,
    unsigned short* __restrict__ PE, float* __restrict__ outF,
    const float* __restrict__ strbuf) {
    cg::grid_group grid = cg::this_grid();
    const int bid = blockIdx.x;
    const int x8 = bid & 7;
    const int wloc = bid >> 3;              // 0..127

#pragma unroll 1
    for (int st = 0; st < 9; ++st) {
        const unsigned short *p0, *p1, *p2 = nullptr;
        unsigned short *d0, *d1 = nullptr;
        int ty;
        switch (st) {
            case 0: p0 = PA; p1 = PB; d0 = PC; ty = 0; break;               // Y0 = a@z0
            case 1: p0 = PB; p1 = PC; d0 = PD; ty = 1; break;               // T0
            case 2: p0 = PC; p1 = PD; p2 = PB; d0 = PA; d1 = PE; ty = 2; break;
            case 3: p0 = PE; p1 = PA; d0 = PB; ty = 1; break;               // T1
            case 4: p0 = PA; p1 = PB; p2 = PE; d0 = PC; d1 = PD; ty = 2; break;
            case 5: p0 = PD; p1 = PC; d0 = PA; ty = 1; break;               // T2
            case 6: p0 = PC; p1 = PA; p2 = PD; d0 = PB; d1 = PE; ty = 2; break;
            case 7: p0 = PE; p1 = PB; d0 = PC; ty = 1; break;               // T3
            default: p0 = PB; p1 = PC; d0 = nullptr; ty = 3; break;         // out
        }

        bool active;
        int b = 0, tm = 0, tn = 0;
        const unsigned short *Am = nullptr, *Bm = nullptr;
        unsigned short* Dm = nullptr;
        if (ty == 2) {
            active = true;
            b = x8 + 8 * ((wloc >> 4) & 3);
            const int zz = wloc >> 6, tile = wloc & 15;
            tm = tile >> 2; tn = tile & 3;
            Am = zz ? p1 : p0;      // T : Y
            Bm = zz ? p2 : p1;      // Z : T
            Dm = zz ? d1 : d0;      // Zn : Yn
        } else if (ty == 3) {
            active = (wloc < 40);
            if (active) {
                b = x8 + 8 * (wloc / 10);
                int p = wloc % 10, rem = 4;
                while (p >= rem) { p -= rem; ++tm; --rem; }
                tn = tm + p;
                Am = p0; Bm = p1;
            }
        } else {
            active = (wloc < 64);
            if (active) {
                b = x8 + 8 * (wloc >> 4);
                const int tile = wloc & 15;
                tm = tile >> 2; tn = tile & 3;
                Am = p0; Bm = p1; Dm = d0;
            }
        }

        if (active) {
            const size_t mo = (size_t)b * 8 * SLAB;
            f4v acc[4][4] = {};
            wave_gemm64(Am + mo, Bm + mo, tm * 64, tn * 64, acc);
            if (ty == 3) {
                const int lane = threadIdx.x & 63, q = lane >> 4, r = lane & 15;
                const float sc = strbuf[b];
#pragma unroll
                for (int i = 0; i < 4; ++i)
#pragma unroll
                    for (int j = 0; j < 4; ++j) {
                        const int gj = tn * 64 + j * 16 + r;
#pragma unroll
                        for (int reg = 0; reg < 4; ++reg) {
                            const int gi = tm * 64 + i * 16 + q * 4 + reg;
                            if (gj >= gi)
                                outF[(size_t)b * OUTROW +
                                     (size_t)(gi * C - (gi * (gi - 1)) / 2) + (gj - gi)] =
                                    acc[i][j][reg] * sc;
                        }
                    }
            } else {
                store_tile_fm(Dm + mo, tm, tn, acc, ty == 1);
            }
        }
        __threadfence();
        grid.sync();
        __threadfence();
    }
}

// ---------------------------------------------------------------------------
extern "C" void kernel_launch(void* const* d_in, const int* in_sizes, int n_in,
                              void* d_out, int out_size, void* d_ws, size_t ws_size,
                              hipStream_t stream) {
    const float* x = (const float*)d_in[0];
    float* out = (float*)d_out;

    unsigned short* W = (unsigned short*)d_ws;
    const size_t XS = (size_t)BATCH * KC32 * SLAB;   // interleaved X shorts
    const size_t MS = (size_t)BATCH * 8 * SLAB;      // one interleaved matrix set
    unsigned short* X = W;
    float* sbuf = (float*)(X + XS);
    float* trbuf = sbuf + BATCH * C;
    float* strbuf = trbuf + BATCH;
    unsigned short* P = (unsigned short*)(strbuf + BATCH);
    unsigned short* PA = P + 0 * MS;
    unsigned short* PB = P + 1 * MS;
    unsigned short* PC = P + 2 * MS;
    unsigned short* PD = P + 3 * MS;
    unsigned short* PE = P + 4 * MS;
    // fp32 gram partials alias PC.. (dead until Y0 is written)
    float* part = (float*)PC;                         // 10*32*7*4096 floats
    // prep sum partials alias PA (dead until k_reduce writes it)
    float* psum = (float*)PA;                         // 32*49*256 floats
    float* qsum = psum + (size_t)BATCH * KCG * 256;

    k_prep<<<dim3(BATCH * KCG), 256, 0, stream>>>(x, X, psum, qsum);
    k_tr<<<dim3(BATCH), 256, 0, stream>>>(psum, qsum, sbuf, trbuf, strbuf);
    k_gram_split<<<dim3(10 * BATCH * KSPLIT), 64, 0, stream>>>(X, part);
    k_reduce<<<dim3(10, BATCH), 256, 0, stream>>>(part, sbuf, trbuf, PA, PB);

    void* args[] = { &PA, &PB, &PC, &PD, &PE, &out, &strbuf };
    hipLaunchCooperativeKernel((const void*)k_ns, dim3(1024), dim3(64), args, 0, stream);
}

// Round 3
// 378.189 us; speedup vs baseline: 5.0173x; 5.0173x over previous
//
#include <hip/hip_runtime.h>
#include <hip/hip_bf16.h>
#include <math.h>

#define BATCH 32
#define C 256
#define HW 3136
#define OUTROW 32896
#define KSPLIT 7
#define KCHUNK 448   // HW / KSPLIT
#define KC32 98      // HW / 32
#define KCG 49       // kc-pair groups per batch
#define SLAB 16384   // shorts per kc slab (hi 8192 + lo 8192 interleaved)
#define HALF 8192

// Interleaved fragment-major layouts (shorts):
//   X slab s = b*98 + kc :  X[s*SLAB + row*32 + (k&31)]        (hi)
//                           X[s*SLAB + HALF + row*32 + (k&31)] (lo)
//   M slab s = b*8 + kc  :  same, 256x256 matrices, 8 slabs each.

typedef __bf16 b8v __attribute__((ext_vector_type(8)));
typedef float  f4v __attribute__((ext_vector_type(4)));
typedef unsigned short u16x8 __attribute__((ext_vector_type(8)));

__device__ __forceinline__ unsigned short f2bf(float f) {
    union { float f; unsigned u; } v; v.f = f;
    unsigned r = v.u + 0x7FFFu + ((v.u >> 16) & 1u);
    return (unsigned short)(r >> 16);
}
__device__ __forceinline__ float bf2f(unsigned short h) {
    union { unsigned u; float f; } v; v.u = ((unsigned)h) << 16; return v.f;
}
__device__ __forceinline__ void split2(float x, unsigned short& h, unsigned short& l) {
    h = f2bf(x);
    l = f2bf(x - bf2f(h));
}

__device__ __forceinline__ float wave_sum(float v) {
    for (int o = 32; o; o >>= 1) v += __shfl_down(v, o, 64);
    return v;
}

// ---------------------------------------------------------------------------
// prep: x -> hi/lo bf16 split, interleaved fragment-major X layout.
// Block per (b, kc-pair): writes one contiguous 64-KB region (2 slabs);
// reads two adjacent 128-B segments per row. Per-(b,row,kcg) partials out.
// ---------------------------------------------------------------------------
__global__ __launch_bounds__(256) void k_prep(const float* __restrict__ x,
                                              unsigned short* __restrict__ X,
                                              float* __restrict__ psum,
                                              float* __restrict__ qsum) {
    const int blk = blockIdx.x;                 // b*KCG + g
    const int b = blk / KCG;
    const int g = blk - b * KCG;
    const int kc0 = g * 2;
    const int t = threadIdx.x;
    const int lane4 = t & 3;                    // 4 lanes per row, 16 floats each
    const int rowoff = t >> 2;                  // 0..63
    const int ko = lane4 * 8;

    const float* xb = x + (size_t)b * C * HW + (size_t)kc0 * 32 + ko;
    unsigned short* s0 = X + (size_t)(b * KC32 + kc0) * SLAB + ko;
    unsigned short* s1 = s0 + SLAB;
    float* ps = psum + (size_t)blk * 256;
    float* qs = qsum + (size_t)blk * 256;

#pragma unroll
    for (int it = 0; it < 4; ++it) {
        const int row = it * 64 + rowoff;
        const float* src = xb + (size_t)row * HW;
        float4 v0 = *(const float4*)(src);
        float4 v1 = *(const float4*)(src + 4);
        float4 v2 = *(const float4*)(src + 32);
        float4 v3 = *(const float4*)(src + 36);
        float va[8] = { v0.x, v0.y, v0.z, v0.w, v1.x, v1.y, v1.z, v1.w };
        float vb[8] = { v2.x, v2.y, v2.z, v2.w, v3.x, v3.y, v3.z, v3.w };
        unsigned short ha[8], la[8], hb[8], lb[8];
        float s = 0.f, q = 0.f;
#pragma unroll
        for (int j = 0; j < 8; ++j) {
            split2(va[j], ha[j], la[j]);
            split2(vb[j], hb[j], lb[j]);
            s += va[j] + vb[j];
            q = fmaf(va[j], va[j], q);
            q = fmaf(vb[j], vb[j], q);
        }
        *(u16x8*)(s0 + row * 32) = *(u16x8*)ha;
        *(u16x8*)(s0 + HALF + row * 32) = *(u16x8*)la;
        *(u16x8*)(s1 + row * 32) = *(u16x8*)hb;
        *(u16x8*)(s1 + HALF + row * 32) = *(u16x8*)lb;
        s += __shfl_xor(s, 1, 64);
        s += __shfl_xor(s, 2, 64);
        q += __shfl_xor(q, 1, 64);
        q += __shfl_xor(q, 2, 64);
        if (lane4 == 0) { ps[row] = s; qs[row] = q; }
    }
}

// reduce per-kcg partials -> sbuf (row sums) + trace
__global__ __launch_bounds__(256) void k_tr(const float* __restrict__ psum,
                                            const float* __restrict__ qsum,
                                            float* __restrict__ sbuf,
                                            float* __restrict__ trbuf,
                                            float* __restrict__ strbuf) {
    const int b = blockIdx.x, t = threadIdx.x;
    const float* ps = psum + (size_t)b * KCG * 256 + t;
    const float* qs = qsum + (size_t)b * KCG * 256 + t;
    float s = 0.f, q = 0.f;
#pragma unroll 7
    for (int g = 0; g < KCG; ++g) {
        s += ps[(size_t)g * 256];
        q += qs[(size_t)g * 256];
    }
    sbuf[b * C + t] = s;
    const float invn = 1.f / (float)HW, invn2 = invn * invn;
    float v = q * invn - s * s * invn2;
    v = wave_sum(v);
    __shared__ float red[4];
    if ((t & 63) == 0) red[t >> 6] = v;
    __syncthreads();
    if (t == 0) {
        float tr = red[0] + red[1] + red[2] + red[3];
        trbuf[b] = tr;
        strbuf[b] = sqrtf(tr);
    }
}

// ---------------------------------------------------------------------------
// gram split-K: 1-wave blocks, 64x64 tile, fragment-major coalesced loads,
// register dbuf, XCD-pinned. Grid 2240 x 64.
// ---------------------------------------------------------------------------
__global__ __launch_bounds__(64) void k_gram_split(
    const unsigned short* __restrict__ X, float* __restrict__ part) {
    const int bid = blockIdx.x;
    const int x8 = bid & 7;
    const int t8 = bid >> 3;
    const int pairIdx = t8 % 10;
    const int g = (t8 / 10) * 8 + x8;   // 0..223, pinned to XCD x8
    const int b = g & 31;
    const int z = g >> 5;               // 0..6

    int p = pairIdx, tm = 0, rem = 4;
    while (p >= rem) { p -= rem; ++tm; --rem; }
    const int tn = tm + p;

    const int lane = threadIdx.x & 63;
    const int q = lane >> 4, r = lane & 15;
    const int kc0 = z * (KCHUNK / 32);
    const size_t matb = (size_t)b * KC32 * SLAB;

    int oA[4], oB[4];
#pragma unroll
    for (int i = 0; i < 4; ++i) {
        oA[i] = (tm * 64 + i * 16 + r) * 32 + q * 8;
        oB[i] = (tn * 64 + i * 16 + r) * 32 + q * 8;
    }

    f4v acc[4][4] = {};
    b8v fAh[2][4], fAl[2][4], fBh[2][4], fBl[2][4];
#define LDG(buf, kc)                                                     \
    do {                                                                 \
        const size_t sb = matb + (size_t)(kc0 + (kc)) * SLAB;            \
        for (int i = 0; i < 4; ++i) {                                    \
            fAh[buf][i] = *(const b8v*)(X + sb + oA[i]);                 \
            fAl[buf][i] = *(const b8v*)(X + sb + HALF + oA[i]);          \
            fBh[buf][i] = *(const b8v*)(X + sb + oB[i]);                 \
            fBl[buf][i] = *(const b8v*)(X + sb + HALF + oB[i]);          \
        }                                                                \
    } while (0)

    LDG(0, 0);
#pragma unroll
    for (int kc = 0; kc < KCHUNK / 32; ++kc) {
        const int cb = kc & 1, nb = cb ^ 1;
        if (kc < KCHUNK / 32 - 1) LDG(nb, kc + 1);
#pragma unroll
        for (int i = 0; i < 4; ++i)
#pragma unroll
            for (int j = 0; j < 4; ++j) {
                acc[i][j] = __builtin_amdgcn_mfma_f32_16x16x32_bf16(fAh[cb][i], fBh[cb][j], acc[i][j], 0, 0, 0);
                acc[i][j] = __builtin_amdgcn_mfma_f32_16x16x32_bf16(fAh[cb][i], fBl[cb][j], acc[i][j], 0, 0, 0);
                acc[i][j] = __builtin_amdgcn_mfma_f32_16x16x32_bf16(fAl[cb][i], fBh[cb][j], acc[i][j], 0, 0, 0);
            }
    }
#undef LDG

    float* pt = part + (((size_t)pairIdx * BATCH + b) * KSPLIT + z) * 4096;
#pragma unroll
    for (int i = 0; i < 4; ++i)
#pragma unroll
        for (int j = 0; j < 4; ++j)
#pragma unroll
            for (int reg = 0; reg < 4; ++reg) {
                int row = i * 16 + q * 4 + reg;
                int col = j * 16 + r;
                pt[row * 64 + col] = acc[i][j][reg];
            }
}

// ---------------------------------------------------------------------------
// reduce partials -> a and z0 (interleaved fragment-major), mirrored via LDS
// ---------------------------------------------------------------------------
__global__ __launch_bounds__(256) void k_reduce(
    const float* __restrict__ part, const float* __restrict__ sbuf,
    const float* __restrict__ trbuf,
    unsigned short* __restrict__ A, unsigned short* __restrict__ Z) {
    const int b = blockIdx.y;
    int p = blockIdx.x, tm = 0, rem = 4;
    while (p >= rem) { p -= rem; ++tm; --rem; }
    const int tn = tm + p;

    const float* pb = part + ((size_t)blockIdx.x * BATCH + b) * KSPLIT * 4096;
    const int t = threadIdx.x;
    const int row = t >> 2, c0 = (t & 3) * 16;

    float s[16];
#pragma unroll
    for (int u = 0; u < 16; ++u) s[u] = 0.f;
    for (int sp = 0; sp < KSPLIT; ++sp) {
        const float* q4 = pb + sp * 4096 + row * 64 + c0;
#pragma unroll
        for (int u4 = 0; u4 < 4; ++u4) {
            float4 v = *(const float4*)(q4 + u4 * 4);
            s[u4 * 4 + 0] += v.x; s[u4 * 4 + 1] += v.y;
            s[u4 * 4 + 2] += v.z; s[u4 * 4 + 3] += v.w;
        }
    }

    const float invn = 1.f / (float)HW, invn2 = invn * invn;
    const float tr = trbuf[b];
    const int gi = tm * 64 + row;
    const float si = sbuf[b * C + gi];
    const size_t mb = (size_t)b * 8 * SLAB;

    __shared__ unsigned short tAh[64][66], tAl[64][66], tZh[64][66], tZl[64][66];
    unsigned short vAh[16], vAl[16], vZh[16], vZl[16];
#pragma unroll
    for (int u = 0; u < 16; ++u) {
        int gj = tn * 64 + c0 + u;
        float sj = sbuf[b * C + gj];
        float a = (s[u] * invn - si * sj * invn2) / tr;
        split2(a, vAh[u], vAl[u]);
        float zv = ((gi == gj) ? 1.5f : 0.f) - 0.5f * a;
        split2(zv, vZh[u], vZl[u]);
        tAh[row][c0 + u] = vAh[u]; tAl[row][c0 + u] = vAl[u];
        tZh[row][c0 + u] = vZh[u]; tZl[row][c0 + u] = vZl[u];
    }
#pragma unroll
    for (int u4 = 0; u4 < 4; ++u4) {
        const int col0 = tn * 64 + c0 + u4 * 4;
        const size_t off = mb + (size_t)(col0 >> 5) * SLAB + (size_t)gi * 32 + (col0 & 31);
        *(ushort4*)&A[off] = *(ushort4*)&vAh[u4 * 4];
        *(ushort4*)&A[off + HALF] = *(ushort4*)&vAl[u4 * 4];
        *(ushort4*)&Z[off] = *(ushort4*)&vZh[u4 * 4];
        *(ushort4*)&Z[off + HALF] = *(ushort4*)&vZl[u4 * 4];
    }
    if (tm != tn) {
        __syncthreads();
        const int mr = t >> 2, mc0 = (t & 3) * 16;
        const int gim = tn * 64 + mr;
        unsigned short wAh[16], wAl[16], wZh[16], wZl[16];
#pragma unroll
        for (int u = 0; u < 16; ++u) {
            wAh[u] = tAh[mc0 + u][mr]; wAl[u] = tAl[mc0 + u][mr];
            wZh[u] = tZh[mc0 + u][mr]; wZl[u] = tZl[mc0 + u][mr];
        }
#pragma unroll
        for (int u4 = 0; u4 < 4; ++u4) {
            const int col0 = tm * 64 + mc0 + u4 * 4;
            const size_t off = mb + (size_t)(col0 >> 5) * SLAB + (size_t)gim * 32 + (col0 & 31);
            *(ushort4*)&A[off] = *(ushort4*)&wAh[u4 * 4];
            *(ushort4*)&A[off + HALF] = *(ushort4*)&wAl[u4 * 4];
            *(ushort4*)&Z[off] = *(ushort4*)&wZh[u4 * 4];
            *(ushort4*)&Z[off + HALF] = *(ushort4*)&wZl[u4 * 4];
        }
    }
}

// ---------------------------------------------------------------------------
// NS core: one wave, 64x64 tile, K=256, interleaved fragment-major loads,
// register dbuf. No barriers in the K-loop.
// ---------------------------------------------------------------------------
__device__ __forceinline__ void wave_gemm64(
    const unsigned short* __restrict__ A, const unsigned short* __restrict__ B,
    int rowA, int rowB, f4v acc[4][4]) {
    const int lane = threadIdx.x & 63;
    const int q = lane >> 4, r = lane & 15;
    int oA[4], oB[4];
#pragma unroll
    for (int i = 0; i < 4; ++i) {
        oA[i] = (rowA + i * 16 + r) * 32 + q * 8;
        oB[i] = (rowB + i * 16 + r) * 32 + q * 8;
    }
    b8v fAh[2][4], fAl[2][4], fBh[2][4], fBl[2][4];
#define LD(buf, kc)                                              \
    do {                                                         \
        const size_t sb = (size_t)(kc) * SLAB;                   \
        for (int i = 0; i < 4; ++i) {                            \
            fAh[buf][i] = *(const b8v*)(A + sb + oA[i]);         \
            fAl[buf][i] = *(const b8v*)(A + sb + HALF + oA[i]);  \
            fBh[buf][i] = *(const b8v*)(B + sb + oB[i]);         \
            fBl[buf][i] = *(const b8v*)(B + sb + HALF + oB[i]);  \
        }                                                        \
    } while (0)

    LD(0, 0);
#pragma unroll
    for (int kc = 0; kc < 8; ++kc) {
        const int cb = kc & 1, nb = cb ^ 1;
        if (kc < 7) LD(nb, kc + 1);
#pragma unroll
        for (int i = 0; i < 4; ++i)
#pragma unroll
            for (int j = 0; j < 4; ++j) {
                acc[i][j] = __builtin_amdgcn_mfma_f32_16x16x32_bf16(fAh[cb][i], fBh[cb][j], acc[i][j], 0, 0, 0);
                acc[i][j] = __builtin_amdgcn_mfma_f32_16x16x32_bf16(fAh[cb][i], fBl[cb][j], acc[i][j], 0, 0, 0);
                acc[i][j] = __builtin_amdgcn_mfma_f32_16x16x32_bf16(fAl[cb][i], fBh[cb][j], acc[i][j], 0, 0, 0);
            }
    }
#undef LD
}

// store one 64x64 result tile into interleaved fragment-major D.
// LDS-staged transpose: 128 scalar global stores -> 16 x 16-B stores/lane.
__device__ __forceinline__ void store_tile_fm(
    unsigned short* __restrict__ D, int tm, int tn, const f4v acc[4][4], bool modeT) {
    __shared__ unsigned short lh[64][68];
    __shared__ unsigned short ll[64][68];
    const int lane = threadIdx.x & 63, q = lane >> 4, r = lane & 15;
#pragma unroll
    for (int i = 0; i < 4; ++i)
#pragma unroll
        for (int j = 0; j < 4; ++j) {
            const int col = j * 16 + r;
#pragma unroll
            for (int reg = 0; reg < 4; ++reg) {
                const int row = i * 16 + q * 4 + reg;
                float v = acc[i][j][reg];
                if (modeT) v = ((tm * 64 + row == tn * 64 + col) ? 1.5f : 0.f) - 0.5f * v;
                unsigned short h, l;
                split2(v, h, l);
                lh[row][col] = h;
                ll[row][col] = l;
            }
        }
    __syncthreads();
    const int rowL = lane;
    const size_t gbase = (size_t)(tm * 64 + rowL) * 32;
#pragma unroll
    for (int c = 0; c < 8; ++c) {
        const int gj0 = tn * 64 + c * 8;
        const size_t off = (size_t)(gj0 >> 5) * SLAB + gbase + (gj0 & 31);
        union { ushort4 u4[2]; u16x8 u8; } hv, lv;
        hv.u4[0] = *(const ushort4*)&lh[rowL][c * 8];
        hv.u4[1] = *(const ushort4*)&lh[rowL][c * 8 + 4];
        lv.u4[0] = *(const ushort4*)&ll[rowL][c * 8];
        lv.u4[1] = *(const ushort4*)&ll[rowL][c * 8 + 4];
        *(u16x8*)&D[off] = hv.u8;
        *(u16x8*)&D[off + HALF] = lv.u8;
    }
}

// MODE 0: D = acc ; MODE 1: D = 1.5I - 0.5 acc ; MODE 2: triuvec(acc*sqrt(tr))
// XCD-pinned flat grid: batch b always lands on XCD b%8.
template <int MODE>
__global__ __launch_bounds__(64) void k_t64(
    const unsigned short* __restrict__ A, const unsigned short* __restrict__ B,
    unsigned short* __restrict__ D, float* __restrict__ outF,
    const float* __restrict__ strbuf) {
    const int bid = blockIdx.x;
    const int x8 = bid & 7;
    const int w = bid >> 3;
    int b, tm = 0, tn = 0;
    if (MODE == 2) {
        b = x8 + 8 * (w / 10);
        int p = w % 10, rem = 4;
        while (p >= rem) { p -= rem; ++tm; --rem; }
        tn = tm + p;
    } else {
        b = x8 + 8 * (w >> 4);
        const int tile = w & 15;
        tm = tile >> 2; tn = tile & 3;
    }
    const size_t mo = (size_t)b * 8 * SLAB;
    f4v acc[4][4] = {};
    wave_gemm64(A + mo, B + mo, tm * 64, tn * 64, acc);

    if (MODE == 2) {
        const int lane = threadIdx.x & 63, q = lane >> 4, r = lane & 15;
        const float sc = strbuf[b];
#pragma unroll
        for (int i = 0; i < 4; ++i)
#pragma unroll
            for (int j = 0; j < 4; ++j) {
                const int gj = tn * 64 + j * 16 + r;
#pragma unroll
                for (int reg = 0; reg < 4; ++reg) {
                    const int gi = tm * 64 + i * 16 + q * 4 + reg;
                    if (gj >= gi)
                        outF[(size_t)b * OUTROW + (size_t)(gi * C - (gi * (gi - 1)) / 2) +
                             (gj - gi)] = acc[i][j][reg] * sc;
                }
            }
    } else {
        store_tile_fm(D + mo, tm, tn, acc, MODE == 1);
    }
}

// fused Ynew = Y@T, Znew = T@Z ; XCD-pinned flat grid (1024 blocks)
__global__ __launch_bounds__(64) void k_yz64(
    const unsigned short* __restrict__ Y, const unsigned short* __restrict__ T,
    const unsigned short* __restrict__ Z,
    unsigned short* __restrict__ Yn, unsigned short* __restrict__ Zn) {
    const int bid = blockIdx.x;
    const int x8 = bid & 7;
    const int w = bid >> 3;                 // 0..127
    const int b = x8 + 8 * ((w >> 4) & 3);
    const int zz = w >> 6;                  // 0: Y@T, 1: T@Z
    const int tile = w & 15;
    const int tm = tile >> 2, tn = tile & 3;

    const unsigned short* Am = zz ? T : Y;
    const unsigned short* Bm = zz ? Z : T;
    unsigned short* Dm = zz ? Zn : Yn;

    const size_t mo = (size_t)b * 8 * SLAB;
    f4v acc[4][4] = {};
    wave_gemm64(Am + mo, Bm + mo, tm * 64, tn * 64, acc);
    store_tile_fm(Dm + mo, tm, tn, acc, false);
}

// ---------------------------------------------------------------------------
extern "C" void kernel_launch(void* const* d_in, const int* in_sizes, int n_in,
                              void* d_out, int out_size, void* d_ws, size_t ws_size,
                              hipStream_t stream) {
    const float* x = (const float*)d_in[0];
    float* out = (float*)d_out;

    unsigned short* W = (unsigned short*)d_ws;
    const size_t XS = (size_t)BATCH * KC32 * SLAB;   // interleaved X shorts
    const size_t MS = (size_t)BATCH * 8 * SLAB;      // one interleaved matrix set
    unsigned short* X = W;
    float* sbuf = (float*)(X + XS);
    float* trbuf = sbuf + BATCH * C;
    float* strbuf = trbuf + BATCH;
    unsigned short* P = (unsigned short*)(strbuf + BATCH);
    unsigned short* PA = P + 0 * MS;
    unsigned short* PB = P + 1 * MS;
    unsigned short* PC = P + 2 * MS;
    unsigned short* PD = P + 3 * MS;
    unsigned short* PE = P + 4 * MS;
    // fp32 gram partials alias PC.. (dead until Y0 is written)
    float* part = (float*)PC;                         // 10*32*7*4096 floats
    // prep sum partials alias PA (dead until k_reduce writes it)
    float* psum = (float*)PA;                         // 32*49*256 floats
    float* qsum = psum + (size_t)BATCH * KCG * 256;

    k_prep<<<dim3(BATCH * KCG), 256, 0, stream>>>(x, X, psum, qsum);
    k_tr<<<dim3(BATCH), 256, 0, stream>>>(psum, qsum, sbuf, trbuf, strbuf);
    k_gram_split<<<dim3(10 * BATCH * KSPLIT), 64, 0, stream>>>(X, part);
    k_reduce<<<dim3(10, BATCH), 256, 0, stream>>>(part, sbuf, trbuf, PA, PB);

    dim3 g512(512);
    // Y0 = a @ z0 -> PC
    k_t64<0><<<g512, 64, 0, stream>>>(PA, PB, PC, nullptr, strbuf);
    // it0: T0 = 1.5I - 0.5 Z0@Y0 = PB@PC -> PD ; Y1 = PC@PD -> PA ; Z1 = PD@PB -> PE
    k_t64<1><<<g512, 64, 0, stream>>>(PB, PC, PD, nullptr, strbuf);
    k_yz64<<<dim3(1024), 64, 0, stream>>>(PC, PD, PB, PA, PE);
    // it1: T1 = PE@PA -> PB ; Y2 = PA@PB -> PC ; Z2 = PB@PE -> PD
    k_t64<1><<<g512, 64, 0, stream>>>(PE, PA, PB, nullptr, strbuf);
    k_yz64<<<dim3(1024), 64, 0, stream>>>(PA, PB, PE, PC, PD);
    // it2: T2 = PD@PC -> PA ; Y3 = PC@PA -> PB ; Z3 = PA@PD -> PE
    k_t64<1><<<g512, 64, 0, stream>>>(PD, PC, PA, nullptr, strbuf);
    k_yz64<<<dim3(1024), 64, 0, stream>>>(PC, PA, PD, PB, PE);
    // it3: T3 = PE@PB -> PC ; out = triuvec((PB@PC) * sqrt(tr))
    k_t64<1><<<g512, 64, 0, stream>>>(PE, PB, PC, nullptr, strbuf);
    k_t64<2><<<dim3(320), 64, 0, stream>>>(PB, PC, nullptr, out, strbuf);
}